// Round 8
// baseline (3021.471 us; speedup 1.0000x reference)
//
#include <hip/hip_runtime.h>
#include <cstdint>
#include <math.h>

#define MASK_VAL (-1e30f)

#define Bb   64
#define VN   100
#define QN   64
#define KN   64
#define VD   2048
#define QD   768
#define KGD  300
#define KGP  320            /* KGD padded to mult of 32 */
#define HH   1024
#define RR   32
#define HDm  32
#define GG   2
#define NBV  (Bb*VN)              /* 6400 */
#define LOGN ((size_t)NBV*QN*KN*GG) /* 52,428,800 */

typedef _Float16 half_t;
typedef _Float16 f16x8 __attribute__((ext_vector_type(8)));
typedef _Float16 f16x4 __attribute__((ext_vector_type(4)));
typedef float    f32x4 __attribute__((ext_vector_type(4)));

#define MFMA_F16(a,b,c) __builtin_amdgcn_mfma_f32_16x16x32_f16(a,b,c,0,0,0)

// ---------------- cast2d ----------------
__global__ __launch_bounds__(256) void cast2d_kernel(const float* __restrict__ src,
                                                     half_t* __restrict__ dst,
                                                     int Rd, int Cd, int Rs, int Cs)
{
  int idx = blockIdx.x*256 + threadIdx.x;
  int total = Rd*Cd;
  if (idx >= total) return;
  int r = idx / Cd, c = idx - r*Cd;
  float v = (r < Rs && c < Cs) ? src[(size_t)r*Cs + c] : 0.f;
  dst[idx] = (half_t)v;
}

// ---------------- castT: dst[n][k] = (k<Ks) ? (half)src[k][n] : 0 ----------------
__global__ __launch_bounds__(256) void castT_kernel(const float* __restrict__ src,
                                                    half_t* __restrict__ dst,
                                                    int Kd, int Ks)
{
  int idx = blockIdx.x*256 + threadIdx.x;
  int total = HH*Kd;
  if (idx >= total) return;
  int n = idx / Kd, k = idx - n*Kd;
  dst[idx] = (half_t)((k < Ks) ? src[(size_t)k*HH + n] : 0.f);
}

// ---------------- permT: Tpp[r][ (zg*32+y)*32 + x ] = (half) T[(r*32+x)*2048 + y*64 + zg] ----
__global__ __launch_bounds__(256) void permT_kernel(const float* __restrict__ Tg,
                                                    half_t* __restrict__ Tpp)
{
  int idx = blockIdx.x*256 + threadIdx.x;
  if (idx >= 32*65536) return;
  int r = idx >> 16, rem = idx & 65535;
  int cp = rem >> 5, x = rem & 31;
  int y = cp & 31, zg = cp >> 5;
  Tpp[idx] = (half_t)Tg[((size_t)(r*32 + x) << 11) + y*64 + zg];
}

// ---------------- mask ----------------
__global__ __launch_bounds__(256) void mask_kernel(const float* __restrict__ v,
                                                   float* __restrict__ maskv)
{
  int row = blockIdx.x;
  int tid = threadIdx.x;
  const float* src = v + (size_t)row * VD;
  float s = 0.f;
  for (int i = tid; i < VD/4; i += 256) {
    float4 x = *(const float4*)&src[i*4];
    s += fabsf(x.x)+fabsf(x.y)+fabsf(x.z)+fabsf(x.w);
  }
#pragma unroll
  for (int off=32; off; off>>=1) s += __shfl_down(s, off);
  __shared__ float red[4];
  if ((tid & 63) == 0) red[tid>>6] = s;
  __syncthreads();
  if (tid == 0) maskv[row] = ((red[0]+red[1]+red[2]+red[3]) == 0.f) ? 1.f : 0.f;
}

// ---------------- proj (MFMA) ----------------
__global__ __launch_bounds__(256) void proj_mfma_kernel(const half_t* __restrict__ A,
                                                        const half_t* __restrict__ Wt,
                                                        const float* __restrict__ bias,
                                                        half_t* __restrict__ H, int Kp)
{
  int w = threadIdx.x >> 6, lane = threadIdx.x & 63;
  int m0 = blockIdx.x*64 + w*16;
  int n0 = blockIdx.y*64;
  int lr = lane & 15, lc = lane >> 4;
  f32x4 acc[4];
#pragma unroll
  for (int nt=0;nt<4;nt++) acc[nt] = (f32x4)(0.f);
  const half_t* arow = A + (size_t)(m0 + lr)*Kp + lc*8;
  for (int k0 = 0; k0 < Kp; k0 += 32) {
    f16x8 a = *(const f16x8*)(arow + k0);
#pragma unroll
    for (int nt = 0; nt < 4; nt++) {
      f16x8 b = *(const f16x8*)(Wt + (size_t)(n0 + nt*16 + lr)*Kp + k0 + lc*8);
      acc[nt] = MFMA_F16(a, b, acc[nt]);
    }
  }
#pragma unroll
  for (int nt = 0; nt < 4; nt++) {
    float bb = bias[n0 + nt*16 + lr];
#pragma unroll
    for (int j = 0; j < 4; j++) {
      float vv = fmaxf(acc[nt][j] + bb, 0.f);
      H[(size_t)(m0 + lc*4 + j)*HH + n0 + nt*16 + lr] = (half_t)vv;
    }
  }
}

// ---------------- triABC v2 (fused stageA+B+C; 4-wave blocks, 2 blocks/CU) -----------------
// grid 1600, 256 thr = 4 waves, wave w -> bv = blockIdx.x*4 + w (never straddles b).
// Per rank: 4 waves cooperatively build u4[bp][4 rows][2048] (wave w covers c'-tiles
// w*32..w*32+31; only D-cols lr<4 stored), double-buffered -> ONE barrier per rank.
// Then each wave: uA from LDS, stage B (wT = mfma(uA,qB)) -> 32-slot rotation LDS
// transpose (R7-verified) -> stage C accumulate. B/C(r) overlaps A(r+1) across waves,
// and 2 resident blocks/CU interleave barrier stalls (R7 had 1 block/CU).
#define VT 4
#define U_ROWSTR 2056                    /* halves */
#define U_BUFB (VT*U_ROWSTR*2)           /* 16448 B per buffer */
#define W_OFF (2*U_BUFB)                 /* 32896 */
#define SMEM_BYTES (W_OFF + 4*2048*4)    /* 65664 B */

__global__ __launch_bounds__(256) void triABC_kernel(const half_t* __restrict__ hq,
                                                     const half_t* __restrict__ hk,
                                                     const half_t* __restrict__ hv,
                                                     const half_t* __restrict__ Tpp,
                                                     const float* __restrict__ maskv,
                                                     float* __restrict__ logits,
                                                     float* __restrict__ pm,
                                                     float* __restrict__ ps)
{
  extern __shared__ char smem[];
  int tid = threadIdx.x;
  int w = tid >> 6, lane = tid & 63;
  int lr = lane & 15, lc = lane >> 4;
  int bv0 = blockIdx.x * VT;
  int bv = bv0 + w;
  int b = bv / VN;

  uint32_t* wme = (uint32_t*)(smem + W_OFF) + w*2048;

  f32x4 acc[2][4][4];
#pragma unroll
  for (int g=0;g<2;g++)
#pragma unroll
    for (int mt=0;mt<4;mt++)
#pragma unroll
      for (int nt=0;nt<4;nt++) acc[g][mt][nt] = (f32x4)(0.f);

  const half_t* qbase = hq + (size_t)(b*QN + lr)*HH + lc*8;
  const half_t* kbase = hk + (size_t)(b*KN + lr)*HH + lc*8;
  const half_t* hvB   = hv + (size_t)(bv0 + lr)*HH + lc*8;       // rows bv0+lr (pad ok)
  const half_t* Tbase = Tpp + (size_t)w*32*512 + lr*32 + lc*8;   // wave's c'-tile range

  // ---- stage A for rank r into buffer bp (lambda-ish macro via immediate code)
  auto stageA = [&](int r, int bp) {
    f16x8 bH = *(const f16x8*)(hvB + r*HDm);
    const half_t* Tw = Tbase + ((size_t)r << 16);
#pragma unroll
    for (int i = 0; i < 32; i++) {
      f16x8 aT = *(const f16x8*)(Tw + i*512);
      f32x4 d = MFMA_F16(aT, bH, (f32x4)(0.f));
      if (lr < VT) {
        f16x4 pk;
        pk[0] = (half_t)d[0]; pk[1] = (half_t)d[1];
        pk[2] = (half_t)d[2]; pk[3] = (half_t)d[3];
        int byteoff = bp*U_BUFB + lr*(U_ROWSTR*2) + (w*32 + i)*32 + lc*8;
        byteoff ^= ((byteoff >> 7) & 7) << 4;
        *(f16x4*)(smem + byteoff) = pk;
      }
    }
  };

  stageA(0, 0);
  __syncthreads();

  for (int r = 0; r < RR; r++) {
    int bp = r & 1;
    // ---- uA frags from LDS (wave's own v-row = w)
    f16x8 uA[4], qB[4], kB[4];
#pragma unroll
    for (int t=0;t<4;t++) {
      int byteoff = bp*U_BUFB + w*(U_ROWSTR*2) + (t*16 + lr)*64 + lc*16;
      byteoff ^= ((byteoff >> 7) & 7) << 4;
      uA[t] = *(const f16x8*)(smem + byteoff);
    }
#pragma unroll
    for (int mt=0;mt<4;mt++) qB[mt] = *(const f16x8*)(qbase + mt*16*HH + r*HDm);
#pragma unroll
    for (int nt=0;nt<4;nt++) kB[nt] = *(const f16x8*)(kbase + nt*16*HH + r*HDm);
    // ---- stage B: wT = mfma(uA, qB) -> 32-slot rotation LDS
#pragma unroll
    for (int t=0;t<4;t++) {
#pragma unroll
      for (int mt=0;mt<4;mt++) {
        f32x4 d = MFMA_F16(uA[t], qB[mt], (f32x4)(0.f));
        union { uint32_t u32; half_t h[2]; } p0, p1;
        p0.h[0] = (half_t)d[0]; p0.h[1] = (half_t)d[2];   // g=0: regs (0,2)
        p1.h[0] = (half_t)d[1]; p1.h[1] = (half_t)d[3];   // g=1: regs (1,3)
        int idx0 = t*8 + mt, idx1 = t*8 + 4 + mt;
        wme[lane*32 + ((idx0 + lane) & 31)] = p0.u32;
        wme[lane*32 + ((idx1 + lane) & 31)] = p1.u32;
      }
    }
    // ---- stage C: am dword s <- src lane (lr+16s), tile t=lc
#pragma unroll
    for (int g=0;g<2;g++) {
      f16x8 am[4];
#pragma unroll
      for (int mt=0;mt<4;mt++) {
        union { uint32_t u[4]; f16x8 v; } amu;
#pragma unroll
        for (int s=0;s<4;s++) {
          int sl = lr + 16*s;
          int idx = lc*8 + g*4 + mt;
          amu.u[s] = wme[sl*32 + ((idx + sl) & 31)];
        }
        am[mt] = amu.v;
      }
#pragma unroll
      for (int mt=0;mt<4;mt++)
#pragma unroll
        for (int nt=0;nt<4;nt++)
          acc[g][mt][nt] = MFMA_F16(am[mt], kB[nt], acc[g][mt][nt]);
    }
    // ---- stage A for next rank into other buffer, then single barrier
    if (r + 1 < RR) stageA(r + 1, bp ^ 1);
    __syncthreads();
  }

  // ---- epilogue: logits (single write), mask, online softmax partials
  float mk = maskv[bv];
  float* lbase = logits + (size_t)bv*QN*KN*GG;
#pragma unroll
  for (int mt=0;mt<4;mt++)
#pragma unroll
    for (int nt=0;nt<4;nt++)
#pragma unroll
      for (int j=0;j<4;j++) {
        size_t off = ((size_t)(mt*16 + lc*4 + j)*KN + nt*16 + lr)*GG;
        float g0 = acc[0][mt][nt][j], g1 = acc[1][mt][nt][j];
        if (mk != 0.f) { g0 = MASK_VAL; g1 = MASK_VAL; }
        *(float2*)(lbase + off) = make_float2(g0, g1);
        acc[0][mt][nt][j] = g0; acc[1][mt][nt][j] = g1;
      }
#pragma unroll
  for (int g=0; g<2; g++) {
    float mloc = acc[g][0][0][0];
#pragma unroll
    for (int mt=0;mt<4;mt++)
#pragma unroll
      for (int nt=0;nt<4;nt++)
#pragma unroll
        for (int j=0;j<4;j++) mloc = fmaxf(mloc, acc[g][mt][nt][j]);
    float sloc = 0.f;
#pragma unroll
    for (int mt=0;mt<4;mt++)
#pragma unroll
      for (int nt=0;nt<4;nt++)
#pragma unroll
        for (int j=0;j<4;j++) sloc += __expf(acc[g][mt][nt][j] - mloc);
#pragma unroll
    for (int off2=1; off2<64; off2<<=1) {
      float m2 = __shfl_xor(mloc, off2);
      float s2 = __shfl_xor(sloc, off2);
      float mn = fmaxf(mloc, m2);
      sloc = sloc*__expf(mloc-mn) + s2*__expf(m2-mn);
      mloc = mn;
    }
    if (lane == 0) { pm[(size_t)bv*GG + g] = mloc; ps[(size_t)bv*GG + g] = sloc; }
  }
}

// ---------------- combine per-(b,g) partials over 100 v ----------------
__global__ __launch_bounds__(64) void combine_kernel(const float* __restrict__ pm,
                                                     const float* __restrict__ ps,
                                                     float* __restrict__ Mg, float* __restrict__ Sg)
{
  int bg = blockIdx.x; int b = bg >> 1, g = bg & 1;
  int lane = threadIdx.x;
  float m = pm[((size_t)b*VN + lane)*GG + g];
  float s = ps[((size_t)b*VN + lane)*GG + g];
  if (lane + 64 < VN) {
    float m2 = pm[((size_t)b*VN + lane + 64)*GG + g];
    float s2 = ps[((size_t)b*VN + lane + 64)*GG + g];
    float mn = fmaxf(m, m2);
    s = s*__expf(m-mn) + s2*__expf(m2-mn); m = mn;
  }
#pragma unroll
  for (int off=1; off<64; off<<=1) {
    float m2 = __shfl_xor(m, off);
    float s2 = __shfl_xor(s, off);
    float mn = fmaxf(m, m2);
    s = s*__expf(m-mn) + s2*__expf(m2-mn);
    m = mn;
  }
  if (lane == 0) { Mg[b*GG+g] = m; Sg[b*GG+g] = s; }
}

// ---------------- p = exp(logits - M)/S ----------------
__global__ __launch_bounds__(256) void pwrite_kernel(const float* __restrict__ logits,
                                                     const float* __restrict__ Mg,
                                                     const float* __restrict__ Sg,
                                                     float* __restrict__ p)
{
  size_t stride = (size_t)gridDim.x * 256;
  const size_t n4 = LOGN/4;
  for (size_t idx = (size_t)blockIdx.x*256 + threadIdx.x; idx < n4; idx += stride){
    size_t e = idx*4;
    int b = (int)(e / ((size_t)VN*QN*KN*GG));
    float M0 = Mg[b*2], M1 = Mg[b*2+1];
    float iS0 = 1.f/Sg[b*2], iS1 = 1.f/Sg[b*2+1];
    float4 x = *(const float4*)&logits[e];
    float4 o;
    o.x = __expf(x.x - M0)*iS0;
    o.y = __expf(x.y - M1)*iS1;
    o.z = __expf(x.z - M0)*iS0;
    o.w = __expf(x.w - M1)*iS1;
    *(float4*)&p[e] = o;
  }
}

extern "C" void kernel_launch(void* const* d_in, const int* in_sizes, int n_in,
                              void* d_out, int out_size, void* d_ws, size_t ws_size,
                              hipStream_t stream)
{
  const float* v   = (const float*)d_in[0];
  const float* q   = (const float*)d_in[1];
  const float* kg  = (const float*)d_in[2];
  const float* Wv  = (const float*)d_in[3];
  const float* bv  = (const float*)d_in[4];
  const float* Wq  = (const float*)d_in[5];
  const float* bq  = (const float*)d_in[6];
  const float* Wkg = (const float*)d_in[7];
  const float* bkg = (const float*)d_in[8];
  const float* Tg  = (const float*)d_in[9];
  float* p_out  = (float*)d_out;
  float* logits = p_out + LOGN;

  char* ws = (char*)d_ws;
  size_t off = 0;
  auto alloc = [&](size_t bytes) -> char* {
    char* ptr = ws + off;
    off = (off + bytes + 255) & ~(size_t)255;
    return ptr;
  };
  half_t* h_v16 = (half_t*)alloc((size_t)(NBV+16)*HH*2);   // +16 rows: stage A over-read
  half_t* h_q16 = (half_t*)alloc((size_t)Bb*QN*HH*2);
  half_t* h_k16 = (half_t*)alloc((size_t)Bb*KN*HH*2);
  half_t* v16   = (half_t*)alloc((size_t)NBV*VD*2);
  half_t* q16   = (half_t*)alloc((size_t)Bb*QN*QD*2);
  half_t* k16   = (half_t*)alloc((size_t)Bb*KN*KGP*2);
  half_t* Wvt   = (half_t*)alloc((size_t)HH*VD*2);
  half_t* Wqt   = (half_t*)alloc((size_t)HH*QD*2);
  half_t* Wkt   = (half_t*)alloc((size_t)HH*KGP*2);
  half_t* Tpp   = (half_t*)alloc((size_t)32*65536*2);
  float* maskv  = (float*)alloc((size_t)NBV*4);
  float* pm     = (float*)alloc((size_t)NBV*GG*4);
  float* ps     = (float*)alloc((size_t)NBV*GG*4);
  float* Mg     = (float*)alloc(128*4);
  float* Sg     = (float*)alloc(128*4);
  (void)ws_size;

  auto nb = [](size_t total) { return (unsigned)((total + 255) / 256); };

  // casts / permute / mask
  cast2d_kernel<<<nb((size_t)NBV*VD),256,0,stream>>>(v,  v16, NBV,   VD,  NBV,   VD);
  cast2d_kernel<<<nb((size_t)Bb*QN*QD),256,0,stream>>>(q,  q16, Bb*QN, QD,  Bb*QN, QD);
  cast2d_kernel<<<nb((size_t)Bb*KN*KGP),256,0,stream>>>(kg, k16, Bb*KN, KGP, Bb*KN, KGD);
  castT_kernel<<<nb((size_t)HH*VD),256,0,stream>>>(Wv,  Wvt, VD,  VD);
  castT_kernel<<<nb((size_t)HH*QD),256,0,stream>>>(Wq,  Wqt, QD,  QD);
  castT_kernel<<<nb((size_t)HH*KGP),256,0,stream>>>(Wkg, Wkt, KGP, KGD);
  permT_kernel<<<nb((size_t)32*65536),256,0,stream>>>(Tg, Tpp);
  mask_kernel<<<NBV,256,0,stream>>>(v, maskv);

  // projections (MFMA)
  proj_mfma_kernel<<<dim3(NBV/64,16),256,0,stream>>>(v16, Wvt, bv,  h_v16, VD);
  proj_mfma_kernel<<<dim3(Bb*QN/64,16),256,0,stream>>>(q16, Wqt, bq,  h_q16, QD);
  proj_mfma_kernel<<<dim3(Bb*KN/64,16),256,0,stream>>>(k16, Wkt, bkg, h_k16, KGP);

  // fused stageA+B+C, all ranks, single dispatch
  hipFuncSetAttribute((const void*)triABC_kernel,
                      hipFuncAttributeMaxDynamicSharedMemorySize, SMEM_BYTES);
  triABC_kernel<<<dim3(NBV/VT),256,SMEM_BYTES,stream>>>(h_q16, h_k16, h_v16, Tpp,
                                                        maskv, logits, pm, ps);

  combine_kernel<<<128,64,0,stream>>>(pm, ps, Mg, Sg);
  pwrite_kernel<<<2048,256,0,stream>>>(logits, Mg, Sg, p_out);
}

// Round 9
// 1277.314 us; speedup vs baseline: 2.3655x; 2.3655x over previous
//
#include <hip/hip_runtime.h>
#include <cstdint>
#include <math.h>

#define MASK_VAL (-1e30f)

#define Bb   64
#define VN   100
#define QN   64
#define KN   64
#define VD   2048
#define QD   768
#define KGD  300
#define KGP  320            /* KGD padded to mult of 32 */
#define HH   1024
#define RR   32
#define HDm  32
#define GG   2
#define NBV  (Bb*VN)              /* 6400 */
#define LOGN ((size_t)NBV*QN*KN*GG) /* 52,428,800 */

typedef _Float16 half_t;
typedef _Float16 f16x8 __attribute__((ext_vector_type(8)));
typedef float    f32x4 __attribute__((ext_vector_type(4)));

#define MFMA_F16(a,b,c) __builtin_amdgcn_mfma_f32_16x16x32_f16(a,b,c,0,0,0)

// ---------------- cast2d ----------------
__global__ __launch_bounds__(256) void cast2d_kernel(const float* __restrict__ src,
                                                     half_t* __restrict__ dst,
                                                     int Rd, int Cd, int Rs, int Cs)
{
  int idx = blockIdx.x*256 + threadIdx.x;
  int total = Rd*Cd;
  if (idx >= total) return;
  int r = idx / Cd, c = idx - r*Cd;
  float v = (r < Rs && c < Cs) ? src[(size_t)r*Cs + c] : 0.f;
  dst[idx] = (half_t)v;
}

// ---------------- castT: dst[n][k] = (k<Ks) ? (half)src[k][n] : 0 ----------------
__global__ __launch_bounds__(256) void castT_kernel(const float* __restrict__ src,
                                                    half_t* __restrict__ dst,
                                                    int Kd, int Ks)
{
  int idx = blockIdx.x*256 + threadIdx.x;
  int total = HH*Kd;
  if (idx >= total) return;
  int n = idx / Kd, k = idx - n*Kd;
  dst[idx] = (half_t)((k < Ks) ? src[(size_t)k*HH + n] : 0.f);
}

// ---------------- permT: Tpp[r][ (zg*32+y)*32 + x ] = (half) T[(r*32+x)*2048 + y*64 + zg] ----
__global__ __launch_bounds__(256) void permT_kernel(const float* __restrict__ Tg,
                                                    half_t* __restrict__ Tpp)
{
  int idx = blockIdx.x*256 + threadIdx.x;
  if (idx >= 32*65536) return;
  int r = idx >> 16, rem = idx & 65535;
  int cp = rem >> 5, x = rem & 31;
  int y = cp & 31, zg = cp >> 5;
  Tpp[idx] = (half_t)Tg[((size_t)(r*32 + x) << 11) + y*64 + zg];
}

// ---------------- mask ----------------
__global__ __launch_bounds__(256) void mask_kernel(const float* __restrict__ v,
                                                   float* __restrict__ maskv)
{
  int row = blockIdx.x;
  int tid = threadIdx.x;
  const float* src = v + (size_t)row * VD;
  float s = 0.f;
  for (int i = tid; i < VD/4; i += 256) {
    float4 x = *(const float4*)&src[i*4];
    s += fabsf(x.x)+fabsf(x.y)+fabsf(x.z)+fabsf(x.w);
  }
#pragma unroll
  for (int off=32; off; off>>=1) s += __shfl_down(s, off);
  __shared__ float red[4];
  if ((tid & 63) == 0) red[tid>>6] = s;
  __syncthreads();
  if (tid == 0) maskv[row] = ((red[0]+red[1]+red[2]+red[3]) == 0.f) ? 1.f : 0.f;
}

// ---------------- proj (MFMA) ----------------
__global__ __launch_bounds__(256) void proj_mfma_kernel(const half_t* __restrict__ A,
                                                        const half_t* __restrict__ Wt,
                                                        const float* __restrict__ bias,
                                                        half_t* __restrict__ H, int Kp)
{
  int w = threadIdx.x >> 6, lane = threadIdx.x & 63;
  int m0 = blockIdx.x*64 + w*16;
  int n0 = blockIdx.y*64;
  int lr = lane & 15, lc = lane >> 4;
  f32x4 acc[4];
#pragma unroll
  for (int nt=0;nt<4;nt++) acc[nt] = (f32x4)(0.f);
  const half_t* arow = A + (size_t)(m0 + lr)*Kp + lc*8;
  for (int k0 = 0; k0 < Kp; k0 += 32) {
    f16x8 a = *(const f16x8*)(arow + k0);
#pragma unroll
    for (int nt = 0; nt < 4; nt++) {
      f16x8 b = *(const f16x8*)(Wt + (size_t)(n0 + nt*16 + lr)*Kp + k0 + lc*8);
      acc[nt] = MFMA_F16(a, b, acc[nt]);
    }
  }
#pragma unroll
  for (int nt = 0; nt < 4; nt++) {
    float bb = bias[n0 + nt*16 + lr];
#pragma unroll
    for (int j = 0; j < 4; j++) {
      float vv = fmaxf(acc[nt][j] + bb, 0.f);
      H[(size_t)(m0 + lc*4 + j)*HH + n0 + nt*16 + lr] = (half_t)vv;
    }
  }
}

// ---------------- stageA (MFMA): u'[rc][bv][c'] = sum_x hv[bv][r*32+x] * T''[r][c'][x] ------
__global__ __launch_bounds__(256) void stageA_mfma_kernel(const half_t* __restrict__ hv,
                                                          const half_t* __restrict__ Tpp,
                                                          half_t* __restrict__ u, int r0)
{
  int rc = blockIdx.z; int r = r0 + rc;
  int w = threadIdx.x >> 6, lane = threadIdx.x & 63;
  int m0 = blockIdx.x*64 + w*16;
  int n0 = blockIdx.y*256;
  int lr = lane & 15, lc = lane >> 4;
  f16x8 a = *(const f16x8*)(hv + (size_t)(m0 + lr)*HH + r*HDm + lc*8);
  const half_t* tb = Tpp + ((size_t)r << 16) + (size_t)n0*32 + lc*8;
  f32x4 acc[16];
#pragma unroll
  for (int nt = 0; nt < 16; nt++) {
    f16x8 b = *(const f16x8*)(tb + nt*16*32 + lr*32);
    acc[nt] = MFMA_F16(a, b, (f32x4)(0.f));
  }
  half_t* ub = u + ((size_t)rc*NBV + m0)*2048 + n0;
#pragma unroll
  for (int nt = 0; nt < 16; nt++) {
#pragma unroll
    for (int j = 0; j < 4; j++) {
      ub[(size_t)(lc*4 + j)*2048 + nt*16 + lr] = (half_t)acc[nt][j];
    }
  }
}

// ---------------- triBC v3: R3 staging/barriers + R4 swapped-B + R7 rotation transpose -----
// grid (25, 64), 256 thr = 4 waves, wave w -> bv = b*100 + vt*4 + w.
// Per rank: [sync] issue u-frag loads; cooperative q/k frag-major staging; [sync];
// stage B: wT[zg][q] = mfma(A=u-frag, B=q-frag); pack (g, z-pair) dwords -> per-wave
// rotation-layout LDS (write banks (idx+l)&31: exactly 2 lanes/bank = free); stage C:
// am dword s from src lane (s*16+lr), idx=lc*8+g*4+mt (read banks also exactly 2-way);
// acc += mfma(am, k-frag). 2 barriers/rank; wme wave-private (lgkmcnt only).
__global__ __launch_bounds__(256) void triBC_mfma_kernel(const half_t* __restrict__ hq,
                                                         const half_t* __restrict__ hk,
                                                         const half_t* __restrict__ u,
                                                         const float* __restrict__ maskv,
                                                         float* __restrict__ logits,
                                                         float* __restrict__ pm,
                                                         float* __restrict__ ps,
                                                         int r0, int RC, int isFirst, int isLast)
{
  __shared__ __align__(16) half_t qtf[2048];
  __shared__ __align__(16) half_t ktf[2048];
  __shared__ uint32_t wlds[4][2048];       // 8KB rotation buffer per wave
  int tid = threadIdx.x;
  int w = tid >> 6, lane = tid & 63;
  uint32_t* wme = wlds[w];
  int vt = blockIdx.x, b = blockIdx.y;
  int bv = b*VN + vt*4 + w;
  int lr = lane & 15, lc = lane >> 4;

  f32x4 acc[2][4][4];
#pragma unroll
  for (int g=0;g<2;g++)
#pragma unroll
    for (int mt=0;mt<4;mt++)
#pragma unroll
      for (int nt=0;nt<4;nt++) acc[g][mt][nt] = (f32x4)(0.f);

  // cooperative staging map: 256 thr stage 64 rows x 32 halves (4 thr/row, 8 halves each)
  int srow = tid >> 2, sch = tid & 3;
  const half_t* qsrc = hq + (size_t)(b*QN + srow)*HH + sch*8;
  const half_t* ksrc = hk + (size_t)(b*KN + srow)*HH + sch*8;
  int sdst = (srow>>4)*512 + ((srow&15) + sch*16)*8;
  // per-lane u fragment base (A-frag: zg=t*16+lr, y=lc*8..)
  const half_t* ubase = u + ((size_t)bv)*2048 + lr*32 + lc*8;

  for (int rc = 0; rc < RC; rc++) {
    int r = r0 + rc;
    __syncthreads();                               // WAR on qtf/ktf
    // u frags (HBM-streaming) issued first; drained at the staging barrier with q/k
    f16x8 ub[4];
#pragma unroll
    for (int t=0;t<4;t++) ub[t] = *(const f16x8*)(ubase + (size_t)rc*NBV*2048 + t*512);
    *(f16x8*)&qtf[sdst] = *(const f16x8*)(qsrc + r*HDm);
    *(f16x8*)&ktf[sdst] = *(const f16x8*)(ksrc + r*HDm);
    __syncthreads();
    f16x8 qb[4], kb[4];
#pragma unroll
    for (int mt=0;mt<4;mt++) qb[mt] = *(const f16x8*)&qtf[mt*512 + lane*8];
#pragma unroll
    for (int nt=0;nt<4;nt++) kb[nt] = *(const f16x8*)&ktf[nt*512 + lane*8];
    // ---- stage B: wT = mfma(ub, qb) -> packed rotation LDS
#pragma unroll
    for (int t=0;t<4;t++) {
#pragma unroll
      for (int mt=0;mt<4;mt++) {
        f32x4 d = MFMA_F16(ub[t], qb[mt], (f32x4)(0.f));
        union { uint32_t u32; half_t h[2]; } p0, p1;
        p0.h[0] = (half_t)d[0]; p0.h[1] = (half_t)d[2];   // g=0: z-pair
        p1.h[0] = (half_t)d[1]; p1.h[1] = (half_t)d[3];   // g=1: z-pair
        int idx0 = t*8 + mt, idx1 = t*8 + 4 + mt;
        wme[lane*32 + ((idx0 + lane) & 31)] = p0.u32;
        wme[lane*32 + ((idx1 + lane) & 31)] = p1.u32;
      }
    }
    // ---- stage C: am dword s <- src lane (s*16+lr), idx = lc*8+g*4+mt
#pragma unroll
    for (int g=0;g<2;g++) {
      f16x8 am[4];
#pragma unroll
      for (int mt=0;mt<4;mt++) {
        union { uint32_t u4[4]; f16x8 v; } amu;
#pragma unroll
        for (int s=0;s<4;s++) {
          int sl = s*16 + lr;
          int idx = lc*8 + g*4 + mt;
          amu.u4[s] = wme[sl*32 + ((idx + sl) & 31)];
        }
        am[mt] = amu.v;
      }
#pragma unroll
      for (int mt=0;mt<4;mt++)
#pragma unroll
        for (int nt=0;nt<4;nt++)
          acc[g][mt][nt] = MFMA_F16(am[mt], kb[nt], acc[g][mt][nt]);
    }
  }

  // ---- epilogue: logits, mask, online softmax partials
  float mk = maskv[bv];
  float* lbase = logits + (size_t)bv*QN*KN*GG;
#pragma unroll
  for (int mt=0;mt<4;mt++)
#pragma unroll
    for (int nt=0;nt<4;nt++)
#pragma unroll
      for (int j=0;j<4;j++) {
        size_t off = ((size_t)(mt*16 + lc*4 + j)*KN + nt*16 + lr)*GG;
        float g0 = acc[0][mt][nt][j], g1 = acc[1][mt][nt][j];
        if (!isFirst) { float2 prev = *(const float2*)(lbase + off); g0 += prev.x; g1 += prev.y; }
        if (isLast && mk != 0.f) { g0 = MASK_VAL; g1 = MASK_VAL; }
        *(float2*)(lbase + off) = make_float2(g0, g1);
        acc[0][mt][nt][j] = g0; acc[1][mt][nt][j] = g1;
      }
  if (isLast) {
#pragma unroll
    for (int g=0; g<2; g++) {
      float mloc = acc[g][0][0][0];
#pragma unroll
      for (int mt=0;mt<4;mt++)
#pragma unroll
        for (int nt=0;nt<4;nt++)
#pragma unroll
          for (int j=0;j<4;j++) mloc = fmaxf(mloc, acc[g][mt][nt][j]);
      float sloc = 0.f;
#pragma unroll
      for (int mt=0;mt<4;mt++)
#pragma unroll
        for (int nt=0;nt<4;nt++)
#pragma unroll
          for (int j=0;j<4;j++) sloc += __expf(acc[g][mt][nt][j] - mloc);
#pragma unroll
      for (int off2=1; off2<64; off2<<=1) {
        float m2 = __shfl_xor(mloc, off2);
        float s2 = __shfl_xor(sloc, off2);
        float mn = fmaxf(mloc, m2);
        sloc = sloc*__expf(mloc-mn) + s2*__expf(m2-mn);
        mloc = mn;
      }
      if (lane == 0) { pm[(size_t)bv*GG + g] = mloc; ps[(size_t)bv*GG + g] = sloc; }
    }
  }
}

// ---------------- combine per-(b,g) partials over 100 v ----------------
__global__ __launch_bounds__(64) void combine_kernel(const float* __restrict__ pm,
                                                     const float* __restrict__ ps,
                                                     float* __restrict__ Mg, float* __restrict__ Sg)
{
  int bg = blockIdx.x; int b = bg >> 1, g = bg & 1;
  int lane = threadIdx.x;
  float m = pm[((size_t)b*VN + lane)*GG + g];
  float s = ps[((size_t)b*VN + lane)*GG + g];
  if (lane + 64 < VN) {
    float m2 = pm[((size_t)b*VN + lane + 64)*GG + g];
    float s2 = ps[((size_t)b*VN + lane + 64)*GG + g];
    float mn = fmaxf(m, m2);
    s = s*__expf(m-mn) + s2*__expf(m2-mn); m = mn;
  }
#pragma unroll
  for (int off=1; off<64; off<<=1) {
    float m2 = __shfl_xor(m, off);
    float s2 = __shfl_xor(s, off);
    float mn = fmaxf(m, m2);
    s = s*__expf(m-mn) + s2*__expf(m2-mn);
    m = mn;
  }
  if (lane == 0) { Mg[b*GG+g] = m; Sg[b*GG+g] = s; }
}

// ---------------- p = exp(logits - M)/S ----------------
__global__ __launch_bounds__(256) void pwrite_kernel(const float* __restrict__ logits,
                                                     const float* __restrict__ Mg,
                                                     const float* __restrict__ Sg,
                                                     float* __restrict__ p)
{
  size_t stride = (size_t)gridDim.x * 256;
  const size_t n4 = LOGN/4;
  for (size_t idx = (size_t)blockIdx.x*256 + threadIdx.x; idx < n4; idx += stride){
    size_t e = idx*4;
    int b = (int)(e / ((size_t)VN*QN*KN*GG));
    float M0 = Mg[b*2], M1 = Mg[b*2+1];
    float iS0 = 1.f/Sg[b*2], iS1 = 1.f/Sg[b*2+1];
    float4 x = *(const float4*)&logits[e];
    float4 o;
    o.x = __expf(x.x - M0)*iS0;
    o.y = __expf(x.y - M1)*iS1;
    o.z = __expf(x.z - M0)*iS0;
    o.w = __expf(x.w - M1)*iS1;
    *(float4*)&p[e] = o;
  }
}

extern "C" void kernel_launch(void* const* d_in, const int* in_sizes, int n_in,
                              void* d_out, int out_size, void* d_ws, size_t ws_size,
                              hipStream_t stream)
{
  const float* v   = (const float*)d_in[0];
  const float* q   = (const float*)d_in[1];
  const float* kg  = (const float*)d_in[2];
  const float* Wv  = (const float*)d_in[3];
  const float* bv  = (const float*)d_in[4];
  const float* Wq  = (const float*)d_in[5];
  const float* bq  = (const float*)d_in[6];
  const float* Wkg = (const float*)d_in[7];
  const float* bkg = (const float*)d_in[8];
  const float* Tg  = (const float*)d_in[9];
  float* p_out  = (float*)d_out;
  float* logits = p_out + LOGN;

  char* ws = (char*)d_ws;
  size_t off = 0;
  auto alloc = [&](size_t bytes) -> char* {
    char* ptr = ws + off;
    off = (off + bytes + 255) & ~(size_t)255;
    return ptr;
  };
  half_t* h_v16 = (half_t*)alloc((size_t)NBV*HH*2);
  half_t* h_q16 = (half_t*)alloc((size_t)Bb*QN*HH*2);
  half_t* h_k16 = (half_t*)alloc((size_t)Bb*KN*HH*2);
  half_t* v16   = (half_t*)alloc((size_t)NBV*VD*2);
  half_t* q16   = (half_t*)alloc((size_t)Bb*QN*QD*2);
  half_t* k16   = (half_t*)alloc((size_t)Bb*KN*KGP*2);
  half_t* Wvt   = (half_t*)alloc((size_t)HH*VD*2);
  half_t* Wqt   = (half_t*)alloc((size_t)HH*QD*2);
  half_t* Wkt   = (half_t*)alloc((size_t)HH*KGP*2);
  half_t* Tpp   = (half_t*)alloc((size_t)32*65536*2);
  float* maskv  = (float*)alloc((size_t)NBV*4);
  float* pm     = (float*)alloc((size_t)NBV*GG*4);
  float* ps     = (float*)alloc((size_t)NBV*GG*4);
  float* Mg     = (float*)alloc(128*4);
  float* Sg     = (float*)alloc(128*4);
  size_t WS_FIXED = off;
  const size_t USZB = (size_t)NBV*2048*2;   // 26,214,400 bytes per r-slice

  int RC; half_t* u;
  if      (WS_FIXED + 32*USZB <= ws_size) { RC = 32; u = (half_t*)(ws + off); }
  else if (WS_FIXED + 16*USZB <= ws_size) { RC = 16; u = (half_t*)(ws + off); }
  else if (WS_FIXED +  8*USZB <= ws_size) { RC =  8; u = (half_t*)(ws + off); }
  else { RC = 8; u = (half_t*)p_out; }      // p region = exactly 8 slices; rewritten at end

  auto nb = [](size_t total) { return (unsigned)((total + 255) / 256); };

  // casts / permute / mask
  cast2d_kernel<<<nb((size_t)NBV*VD),256,0,stream>>>(v,  v16, NBV,   VD,  NBV,   VD);
  cast2d_kernel<<<nb((size_t)Bb*QN*QD),256,0,stream>>>(q,  q16, Bb*QN, QD,  Bb*QN, QD);
  cast2d_kernel<<<nb((size_t)Bb*KN*KGP),256,0,stream>>>(kg, k16, Bb*KN, KGP, Bb*KN, KGD);
  castT_kernel<<<nb((size_t)HH*VD),256,0,stream>>>(Wv,  Wvt, VD,  VD);
  castT_kernel<<<nb((size_t)HH*QD),256,0,stream>>>(Wq,  Wqt, QD,  QD);
  castT_kernel<<<nb((size_t)HH*KGP),256,0,stream>>>(Wkg, Wkt, KGP, KGD);
  permT_kernel<<<nb((size_t)32*65536),256,0,stream>>>(Tg, Tpp);
  mask_kernel<<<NBV,256,0,stream>>>(v, maskv);

  // projections (MFMA)
  proj_mfma_kernel<<<dim3(NBV/64,16),256,0,stream>>>(v16, Wvt, bv,  h_v16, VD);
  proj_mfma_kernel<<<dim3(Bb*QN/64,16),256,0,stream>>>(q16, Wqt, bq,  h_q16, QD);
  proj_mfma_kernel<<<dim3(Bb*KN/64,16),256,0,stream>>>(k16, Wkt, bkg, h_k16, KGP);

  for (int r0 = 0; r0 < RR; r0 += RC) {
    stageA_mfma_kernel<<<dim3(100,8,RC),256,0,stream>>>(h_v16, Tpp, u, r0);
    triBC_mfma_kernel<<<dim3(25,Bb),256,0,stream>>>(h_q16, h_k16, u, maskv, logits, pm, ps,
                                                    r0, RC, (r0==0)?1:0, (r0+RC>=RR)?1:0);
  }
  combine_kernel<<<128,64,0,stream>>>(pm, ps, Mg, Sg);
  pwrite_kernel<<<2048,256,0,stream>>>(logits, Mg, Sg, p_out);
}

// Round 10
// 1200.790 us; speedup vs baseline: 2.5162x; 1.0637x over previous
//
#include <hip/hip_runtime.h>
#include <cstdint>
#include <math.h>

#define MASK_VAL (-1e30f)

#define Bb   64
#define VN   100
#define QN   64
#define KN   64
#define VD   2048
#define QD   768
#define KGD  300
#define KGP  320            /* KGD padded to mult of 32 */
#define HH   1024
#define RR   32
#define HDm  32
#define GG   2
#define NBV  (Bb*VN)              /* 6400 */
#define LOGN ((size_t)NBV*QN*KN*GG) /* 52,428,800 */

typedef _Float16 half_t;
typedef _Float16 f16x8 __attribute__((ext_vector_type(8)));
typedef _Float16 f16x4 __attribute__((ext_vector_type(4)));
typedef float    f32x4 __attribute__((ext_vector_type(4)));

#define MFMA_F16(a,b,c) __builtin_amdgcn_mfma_f32_16x16x32_f16(a,b,c,0,0,0)

// ---------------- preproc (fused casts + weight transposes + T permute) ----------------
#define PN0 13107200   /* v16  : NBV*VD        */
#define PN1 3145728    /* q16  : 4096*QD       */
#define PN2 1310720    /* k16  : 4096*KGP      */
#define PN3 2097152    /* Wvt  : HH*VD         */
#define PN4 786432     /* Wqt  : HH*QD         */
#define PN5 327680     /* Wkt  : HH*KGP        */
#define PN6 2097152    /* Tpp  : 32*65536      */
#define PTOT (PN0+PN1+PN2+PN3+PN4+PN5+PN6)

__global__ __launch_bounds__(256) void preproc_kernel(const float* __restrict__ v,
                                                      const float* __restrict__ q,
                                                      const float* __restrict__ kg,
                                                      const float* __restrict__ Wv,
                                                      const float* __restrict__ Wq,
                                                      const float* __restrict__ Wkg,
                                                      const float* __restrict__ Tg,
                                                      half_t* __restrict__ v16,
                                                      half_t* __restrict__ q16,
                                                      half_t* __restrict__ k16,
                                                      half_t* __restrict__ Wvt,
                                                      half_t* __restrict__ Wqt,
                                                      half_t* __restrict__ Wkt,
                                                      half_t* __restrict__ Tpp)
{
  long idx = (long)blockIdx.x*256 + threadIdx.x;
  if (idx >= PTOT) return;
  if (idx < PN0) { v16[idx] = (half_t)v[idx]; return; }
  idx -= PN0;
  if (idx < PN1) { q16[idx] = (half_t)q[idx]; return; }
  idx -= PN1;
  if (idx < PN2) {
    int r = (int)(idx / KGP), c = (int)(idx - (long)r*KGP);
    k16[idx] = (half_t)((c < KGD) ? kg[(size_t)r*KGD + c] : 0.f);
    return;
  }
  idx -= PN2;
  if (idx < PN3) {
    int n = (int)(idx / VD), k = (int)(idx - (long)n*VD);
    Wvt[idx] = (half_t)Wv[(size_t)k*HH + n];
    return;
  }
  idx -= PN3;
  if (idx < PN4) {
    int n = (int)(idx / QD), k = (int)(idx - (long)n*QD);
    Wqt[idx] = (half_t)Wq[(size_t)k*HH + n];
    return;
  }
  idx -= PN4;
  if (idx < PN5) {
    int n = (int)(idx / KGP), k = (int)(idx - (long)n*KGP);
    Wkt[idx] = (half_t)((k < KGD) ? Wkg[(size_t)k*HH + n] : 0.f);
    return;
  }
  idx -= PN5;
  {
    int r = (int)(idx >> 16), rem = (int)(idx & 65535);
    int cp = rem >> 5, x = rem & 31;
    int y = cp & 31, zg = cp >> 5;
    Tpp[idx + (size_t)0] = (half_t)Tg[((size_t)(r*32 + x) << 11) + y*64 + zg];
  }
}

// ---------------- mask ----------------
__global__ __launch_bounds__(256) void mask_kernel(const float* __restrict__ v,
                                                   float* __restrict__ maskv)
{
  int row = blockIdx.x;
  int tid = threadIdx.x;
  const float* src = v + (size_t)row * VD;
  float s = 0.f;
  for (int i = tid; i < VD/4; i += 256) {
    float4 x = *(const float4*)&src[i*4];
    s += fabsf(x.x)+fabsf(x.y)+fabsf(x.z)+fabsf(x.w);
  }
#pragma unroll
  for (int off=32; off; off>>=1) s += __shfl_down(s, off);
  __shared__ float red[4];
  if ((tid & 63) == 0) red[tid>>6] = s;
  __syncthreads();
  if (tid == 0) maskv[row] = ((red[0]+red[1]+red[2]+red[3]) == 0.f) ? 1.f : 0.f;
}

// ---------------- proj (MFMA, 3 GEMMs fused via blockIdx.z) ----------------
__global__ __launch_bounds__(256) void proj_mfma_kernel(const half_t* __restrict__ A0,
                                                        const half_t* __restrict__ A1,
                                                        const half_t* __restrict__ A2,
                                                        const half_t* __restrict__ W0,
                                                        const half_t* __restrict__ W1,
                                                        const half_t* __restrict__ W2,
                                                        const float* __restrict__ b0p,
                                                        const float* __restrict__ b1p,
                                                        const float* __restrict__ b2p,
                                                        half_t* __restrict__ H0,
                                                        half_t* __restrict__ H1,
                                                        half_t* __restrict__ H2)
{
  int z = blockIdx.z;
  int Mb = (z == 0) ? 100 : 64;
  if ((int)blockIdx.x >= Mb) return;
  const half_t* A  = (z==0) ? A0 : (z==1) ? A1 : A2;
  const half_t* Wt = (z==0) ? W0 : (z==1) ? W1 : W2;
  const float* bias = (z==0) ? b0p : (z==1) ? b1p : b2p;
  half_t* H = (z==0) ? H0 : (z==1) ? H1 : H2;
  int Kp = (z==0) ? VD : (z==1) ? QD : KGP;

  int w = threadIdx.x >> 6, lane = threadIdx.x & 63;
  int m0 = blockIdx.x*64 + w*16;
  int n0 = blockIdx.y*64;
  int lr = lane & 15, lc = lane >> 4;
  f32x4 acc[4];
#pragma unroll
  for (int nt=0;nt<4;nt++) acc[nt] = (f32x4)(0.f);
  const half_t* arow = A + (size_t)(m0 + lr)*Kp + lc*8;
  for (int k0 = 0; k0 < Kp; k0 += 32) {
    f16x8 a = *(const f16x8*)(arow + k0);
#pragma unroll
    for (int nt = 0; nt < 4; nt++) {
      f16x8 b = *(const f16x8*)(Wt + (size_t)(n0 + nt*16 + lr)*Kp + k0 + lc*8);
      acc[nt] = MFMA_F16(a, b, acc[nt]);
    }
  }
#pragma unroll
  for (int nt = 0; nt < 4; nt++) {
    float bb = bias[n0 + nt*16 + lr];
#pragma unroll
    for (int j = 0; j < 4; j++) {
      float vv = fmaxf(acc[nt][j] + bb, 0.f);
      H[(size_t)(m0 + lc*4 + j)*HH + n0 + nt*16 + lr] = (half_t)vv;
    }
  }
}

// ---------------- stageA v2 (swapped operands -> b64 coalesced-per-lane stores) ------------
// grid (100, 8, RC), 256 thr = 4 waves; wave = 16 bv-rows x 256 c'.
// A = T-frag (m = c' within tile), B = hv-frag (n = bv row) -> D[m=c'][n=bv]:
// lane (lr,lc) holds 4 consecutive c' (lc*4+j) for bv row m0+lr -> one f16x4 store per tile.
__global__ __launch_bounds__(256) void stageA_mfma_kernel(const half_t* __restrict__ hv,
                                                          const half_t* __restrict__ Tpp,
                                                          half_t* __restrict__ u, int r0)
{
  int rc = blockIdx.z; int r = r0 + rc;
  int w = threadIdx.x >> 6, lane = threadIdx.x & 63;
  int m0 = blockIdx.x*64 + w*16;
  int n0 = blockIdx.y*256;
  int lr = lane & 15, lc = lane >> 4;
  f16x8 bH = *(const f16x8*)(hv + (size_t)(m0 + lr)*HH + r*HDm + lc*8);
  const half_t* ta = Tpp + ((size_t)r << 16) + (size_t)n0*32 + lr*32 + lc*8;
  half_t* ub = u + ((size_t)rc*NBV + m0 + lr)*2048 + n0 + lc*4;
#pragma unroll
  for (int t = 0; t < 16; t++) {
    f16x8 aT = *(const f16x8*)(ta + t*512);
    f32x4 d = MFMA_F16(aT, bH, (f32x4)(0.f));
    f16x4 pk;
    pk[0] = (half_t)d[0]; pk[1] = (half_t)d[1];
    pk[2] = (half_t)d[2]; pk[3] = (half_t)d[3];
    *(f16x4*)(ub + t*16) = pk;
  }
}

// ---------------- triBC (byte-exact R3 version: 350 us measured) ----------------
#define WSTRIDE 2080   /* halves per g-plane in w frag buffer (pad vs 2048 to split banks) */
__global__ __launch_bounds__(256,2) void triBC_mfma_kernel(const half_t* __restrict__ hq,
                                                           const half_t* __restrict__ hk,
                                                           const half_t* __restrict__ u,
                                                           const float* __restrict__ maskv,
                                                           float* __restrict__ logits,
                                                           float* __restrict__ pm,
                                                           float* __restrict__ ps,
                                                           int r0, int RC, int isFirst, int isLast)
{
  __shared__ __align__(16) half_t smem[2048 + 2048 + 4*2*WSTRIDE];
  half_t* qtf = smem;
  half_t* ktf = smem + 2048;
  int tid = threadIdx.x;
  int w = tid >> 6, lane = tid & 63;
  half_t* wme = smem + 4096 + w*(2*WSTRIDE);
  int vt = blockIdx.x, b = blockIdx.y;
  int bv = b*VN + vt*4 + w;
  int lr = lane & 15, lc = lane >> 4;

  f32x4 acc[2][4][4];
#pragma unroll
  for (int g=0;g<2;g++)
#pragma unroll
    for (int mt=0;mt<4;mt++)
#pragma unroll
      for (int nt=0;nt<4;nt++) acc[g][mt][nt] = (f32x4)(0.f);

  // staging map: 256 threads stage 64 rows x 32 halves (4 thr/row, 8 halves each)
  int srow = tid >> 2, sch = tid & 3;
  const half_t* qsrc = hq + (size_t)(b*QN + srow)*HH + sch*8;
  const half_t* ksrc = hk + (size_t)(b*KN + srow)*HH + sch*8;
  int sdst = (srow>>4)*512 + ((srow&15) + sch*16)*8;

  for (int rc = 0; rc < RC; rc++) {
    int r = r0 + rc;
    __syncthreads();                                   // prev rank's C done
    // issue u' fragment loads early (coalesced 1KB per tile)
    const half_t* up = u + ((size_t)rc*NBV + bv)*2048;
    f16x8 ub[4];
#pragma unroll
    for (int nt=0;nt<4;nt++) ub[nt] = *(const f16x8*)(up + (nt*16+lr)*HDm + lc*8);
    // stage qt/kt frag-major
    *(f16x8*)&qtf[sdst] = *(const f16x8*)(qsrc + r*HDm);
    *(f16x8*)&ktf[sdst] = *(const f16x8*)(ksrc + r*HDm);
    __syncthreads();
    // stage B: w[q][zg] = sum_y qt[q][y] * u[y][zg]
    f16x8 qa[4];
#pragma unroll
    for (int mt=0;mt<4;mt++) qa[mt] = *(const f16x8*)&qtf[mt*512 + lane*8];
#pragma unroll
    for (int nt=0;nt<4;nt++) {
      f32x4 wv[4];
#pragma unroll
      for (int mt=0;mt<4;mt++) wv[mt] = MFMA_F16(qa[mt], ub[nt], (f32x4)(0.f));
      // scatter to frag-major fp16: g = lr&1, slot j = lr>>1
#pragma unroll
      for (int mt=0;mt<4;mt++) {
#pragma unroll
        for (int j=0;j<4;j++) {
          int dst = (lr&1)*WSTRIDE + mt*512 + (lc*4 + j + nt*16)*8 + (lr>>1);
          wme[dst] = (half_t)wv[mt][j];
        }
      }
    }
    __syncthreads();
    // stage C: logits[q][k][g] += sum_z w_g[q][z] * kt[k][z]
    f16x8 bk[4];
#pragma unroll
    for (int nt=0;nt<4;nt++) bk[nt] = *(const f16x8*)&ktf[nt*512 + lane*8];
#pragma unroll
    for (int g=0;g<2;g++) {
      f16x8 am[4];
#pragma unroll
      for (int mt=0;mt<4;mt++) am[mt] = *(const f16x8*)&wme[g*WSTRIDE + mt*512 + lane*8];
#pragma unroll
      for (int mt=0;mt<4;mt++)
#pragma unroll
        for (int nt=0;nt<4;nt++)
          acc[g][mt][nt] = MFMA_F16(am[mt], bk[nt], acc[g][mt][nt]);
    }
  }

  // epilogue
  float mk = maskv[bv];
  float* lbase = logits + (size_t)bv*QN*KN*GG;
#pragma unroll
  for (int mt=0;mt<4;mt++)
#pragma unroll
    for (int nt=0;nt<4;nt++)
#pragma unroll
      for (int j=0;j<4;j++) {
        size_t off = ((size_t)(mt*16 + lc*4 + j)*KN + nt*16 + lr)*GG;
        float g0 = acc[0][mt][nt][j], g1 = acc[1][mt][nt][j];
        if (!isFirst) { float2 prev = *(const float2*)(lbase + off); g0 += prev.x; g1 += prev.y; }
        if (isLast && mk != 0.f) { g0 = MASK_VAL; g1 = MASK_VAL; }
        *(float2*)(lbase + off) = make_float2(g0, g1);
        acc[0][mt][nt][j] = g0; acc[1][mt][nt][j] = g1;
      }
  if (isLast) {
#pragma unroll
    for (int g=0; g<2; g++) {
      float mloc = acc[g][0][0][0];
#pragma unroll
      for (int mt=0;mt<4;mt++)
#pragma unroll
        for (int nt=0;nt<4;nt++)
#pragma unroll
          for (int j=0;j<4;j++) mloc = fmaxf(mloc, acc[g][mt][nt][j]);
      float sloc = 0.f;
#pragma unroll
      for (int mt=0;mt<4;mt++)
#pragma unroll
        for (int nt=0;nt<4;nt++)
#pragma unroll
          for (int j=0;j<4;j++) sloc += __expf(acc[g][mt][nt][j] - mloc);
#pragma unroll
      for (int off2=1; off2<64; off2<<=1) {
        float m2 = __shfl_xor(mloc, off2);
        float s2 = __shfl_xor(sloc, off2);
        float mn = fmaxf(mloc, m2);
        sloc = sloc*__expf(mloc-mn) + s2*__expf(m2-mn);
        mloc = mn;
      }
      if (lane == 0) { pm[(size_t)bv*GG + g] = mloc; ps[(size_t)bv*GG + g] = sloc; }
    }
  }
}

// ---------------- combine per-(b,g) partials over 100 v ----------------
__global__ __launch_bounds__(64) void combine_kernel(const float* __restrict__ pm,
                                                     const float* __restrict__ ps,
                                                     float* __restrict__ Mg, float* __restrict__ Sg)
{
  int bg = blockIdx.x; int b = bg >> 1, g = bg & 1;
  int lane = threadIdx.x;
  float m = pm[((size_t)b*VN + lane)*GG + g];
  float s = ps[((size_t)b*VN + lane)*GG + g];
  if (lane + 64 < VN) {
    float m2 = pm[((size_t)b*VN + lane + 64)*GG + g];
    float s2 = ps[((size_t)b*VN + lane + 64)*GG + g];
    float mn = fmaxf(m, m2);
    s = s*__expf(m-mn) + s2*__expf(m2-mn); m = mn;
  }
#pragma unroll
  for (int off=1; off<64; off<<=1) {
    float m2 = __shfl_xor(m, off);
    float s2 = __shfl_xor(s, off);
    float mn = fmaxf(m, m2);
    s = s*__expf(m-mn) + s2*__expf(m2-mn);
    m = mn;
  }
  if (lane == 0) { Mg[b*GG+g] = m; Sg[b*GG+g] = s; }
}

// ---------------- p = exp(logits - M)/S ----------------
__global__ __launch_bounds__(256) void pwrite_kernel(const float* __restrict__ logits,
                                                     const float* __restrict__ Mg,
                                                     const float* __restrict__ Sg,
                                                     float* __restrict__ p)
{
  size_t stride = (size_t)gridDim.x * 256;
  const size_t n4 = LOGN/4;
  for (size_t idx = (size_t)blockIdx.x*256 + threadIdx.x; idx < n4; idx += stride){
    size_t e = idx*4;
    int b = (int)(e / ((size_t)VN*QN*KN*GG));
    float M0 = Mg[b*2], M1 = Mg[b*2+1];
    float iS0 = 1.f/Sg[b*2], iS1 = 1.f/Sg[b*2+1];
    float4 x = *(const float4*)&logits[e];
    float4 o;
    o.x = __expf(x.x - M0)*iS0;
    o.y = __expf(x.y - M1)*iS1;
    o.z = __expf(x.z - M0)*iS0;
    o.w = __expf(x.w - M1)*iS1;
    *(float4*)&p[e] = o;
  }
}

extern "C" void kernel_launch(void* const* d_in, const int* in_sizes, int n_in,
                              void* d_out, int out_size, void* d_ws, size_t ws_size,
                              hipStream_t stream)
{
  const float* v   = (const float*)d_in[0];
  const float* q   = (const float*)d_in[1];
  const float* kg  = (const float*)d_in[2];
  const float* Wv  = (const float*)d_in[3];
  const float* bv  = (const float*)d_in[4];
  const float* Wq  = (const float*)d_in[5];
  const float* bq  = (const float*)d_in[6];
  const float* Wkg = (const float*)d_in[7];
  const float* bkg = (const float*)d_in[8];
  const float* Tg  = (const float*)d_in[9];
  float* p_out  = (float*)d_out;
  float* logits = p_out + LOGN;

  char* ws = (char*)d_ws;
  size_t off = 0;
  auto alloc = [&](size_t bytes) -> char* {
    char* ptr = ws + off;
    off = (off + bytes + 255) & ~(size_t)255;
    return ptr;
  };
  half_t* h_v16 = (half_t*)alloc((size_t)NBV*HH*2);
  half_t* h_q16 = (half_t*)alloc((size_t)Bb*QN*HH*2);
  half_t* h_k16 = (half_t*)alloc((size_t)Bb*KN*HH*2);
  half_t* v16   = (half_t*)alloc((size_t)NBV*VD*2);
  half_t* q16   = (half_t*)alloc((size_t)Bb*QN*QD*2);
  half_t* k16   = (half_t*)alloc((size_t)Bb*KN*KGP*2);
  half_t* Wvt   = (half_t*)alloc((size_t)HH*VD*2);
  half_t* Wqt   = (half_t*)alloc((size_t)HH*QD*2);
  half_t* Wkt   = (half_t*)alloc((size_t)HH*KGP*2);
  half_t* Tpp   = (half_t*)alloc((size_t)32*65536*2);
  float* maskv  = (float*)alloc((size_t)NBV*4);
  float* pm     = (float*)alloc((size_t)NBV*GG*4);
  float* ps     = (float*)alloc((size_t)NBV*GG*4);
  float* Mg     = (float*)alloc(128*4);
  float* Sg     = (float*)alloc(128*4);
  size_t WS_FIXED = off;
  const size_t USZB = (size_t)NBV*2048*2;   // 26,214,400 bytes per r-slice

  int RC; half_t* u;
  if      (WS_FIXED + 32*USZB <= ws_size) { RC = 32; u = (half_t*)(ws + off); }
  else if (WS_FIXED + 16*USZB <= ws_size) { RC = 16; u = (half_t*)(ws + off); }
  else if (WS_FIXED +  8*USZB <= ws_size) { RC =  8; u = (half_t*)(ws + off); }
  else { RC = 8; u = (half_t*)p_out; }      // p region = exactly 8 slices; rewritten at end

  // fused preproc + mask
  preproc_kernel<<<(unsigned)((PTOT + 255)/256),256,0,stream>>>(v, q, kg, Wv, Wq, Wkg, Tg,
                                                                v16, q16, k16, Wvt, Wqt, Wkt, Tpp);
  mask_kernel<<<NBV,256,0,stream>>>(v, maskv);

  // fused projections (z = 0:v, 1:q, 2:kg)
  proj_mfma_kernel<<<dim3(100,16,3),256,0,stream>>>(v16, q16, k16, Wvt, Wqt, Wkt,
                                                    bv, bq, bkg, h_v16, h_q16, h_k16);

  for (int r0 = 0; r0 < RR; r0 += RC) {
    stageA_mfma_kernel<<<dim3(100,8,RC),256,0,stream>>>(h_v16, Tpp, u, r0);
    triBC_mfma_kernel<<<dim3(25,Bb),256,0,stream>>>(h_q16, h_k16, u, maskv, logits, pm, ps,
                                                    r0, RC, (r0==0)?1:0, (r0+RC>=RR)?1:0);
  }
  combine_kernel<<<128,64,0,stream>>>(pm, ps, Mg, Sg);
  pwrite_kernel<<<2048,256,0,stream>>>(logits, Mg, Sg, p_out);
}

// Round 11
// 997.808 us; speedup vs baseline: 3.0281x; 1.2034x over previous
//
#include <hip/hip_runtime.h>
#include <cstdint>
#include <math.h>

#define MASK_VAL (-1e30f)

#define Bb   64
#define VN   100
#define QN   64
#define KN   64
#define VD   2048
#define QD   768
#define KGD  300
#define KGP  320            /* KGD padded to mult of 32 */
#define HH   1024
#define RR   32
#define HDm  32
#define GG   2
#define NBV  (Bb*VN)              /* 6400 */
#define LOGN ((size_t)NBV*QN*KN*GG) /* 52,428,800 */

typedef _Float16 half_t;
typedef _Float16 f16x8 __attribute__((ext_vector_type(8)));
typedef _Float16 f16x4 __attribute__((ext_vector_type(4)));
typedef float    f32x4 __attribute__((ext_vector_type(4)));

#define MFMA_F16(a,b,c) __builtin_amdgcn_mfma_f32_16x16x32_f16(a,b,c,0,0,0)

// ---------------- preproc (fused casts + weight transposes + T permute) ----------------
#define PN0 13107200   /* v16  : NBV*VD        */
#define PN1 3145728    /* q16  : 4096*QD       */
#define PN2 1310720    /* k16  : 4096*KGP      */
#define PN3 2097152    /* Wvt  : HH*VD         */
#define PN4 786432     /* Wqt  : HH*QD         */
#define PN5 327680     /* Wkt  : HH*KGP        */
#define PN6 2097152    /* Tpp  : 32*65536      */
#define PTOT (PN0+PN1+PN2+PN3+PN4+PN5+PN6)

__global__ __launch_bounds__(256) void preproc_kernel(const float* __restrict__ v,
                                                      const float* __restrict__ q,
                                                      const float* __restrict__ kg,
                                                      const float* __restrict__ Wv,
                                                      const float* __restrict__ Wq,
                                                      const float* __restrict__ Wkg,
                                                      const float* __restrict__ Tg,
                                                      half_t* __restrict__ v16,
                                                      half_t* __restrict__ q16,
                                                      half_t* __restrict__ k16,
                                                      half_t* __restrict__ Wvt,
                                                      half_t* __restrict__ Wqt,
                                                      half_t* __restrict__ Wkt,
                                                      half_t* __restrict__ Tpp)
{
  long idx = (long)blockIdx.x*256 + threadIdx.x;
  if (idx >= PTOT) return;
  if (idx < PN0) { v16[idx] = (half_t)v[idx]; return; }
  idx -= PN0;
  if (idx < PN1) { q16[idx] = (half_t)q[idx]; return; }
  idx -= PN1;
  if (idx < PN2) {
    int r = (int)(idx / KGP), c = (int)(idx - (long)r*KGP);
    k16[idx] = (half_t)((c < KGD) ? kg[(size_t)r*KGD + c] : 0.f);
    return;
  }
  idx -= PN2;
  if (idx < PN3) {
    int n = (int)(idx / VD), k = (int)(idx - (long)n*VD);
    Wvt[idx] = (half_t)Wv[(size_t)k*HH + n];
    return;
  }
  idx -= PN3;
  if (idx < PN4) {
    int n = (int)(idx / QD), k = (int)(idx - (long)n*QD);
    Wqt[idx] = (half_t)Wq[(size_t)k*HH + n];
    return;
  }
  idx -= PN4;
  if (idx < PN5) {
    int n = (int)(idx / KGP), k = (int)(idx - (long)n*KGP);
    Wkt[idx] = (half_t)((k < KGD) ? Wkg[(size_t)k*HH + n] : 0.f);
    return;
  }
  idx -= PN5;
  {
    int r = (int)(idx >> 16), rem = (int)(idx & 65535);
    int cp = rem >> 5, x = rem & 31;
    int y = cp & 31, zg = cp >> 5;
    Tpp[idx + (size_t)0] = (half_t)Tg[((size_t)(r*32 + x) << 11) + y*64 + zg];
  }
}

// ---------------- mask ----------------
__global__ __launch_bounds__(256) void mask_kernel(const float* __restrict__ v,
                                                   float* __restrict__ maskv)
{
  int row = blockIdx.x;
  int tid = threadIdx.x;
  const float* src = v + (size_t)row * VD;
  float s = 0.f;
  for (int i = tid; i < VD/4; i += 256) {
    float4 x = *(const float4*)&src[i*4];
    s += fabsf(x.x)+fabsf(x.y)+fabsf(x.z)+fabsf(x.w);
  }
#pragma unroll
  for (int off=32; off; off>>=1) s += __shfl_down(s, off);
  __shared__ float red[4];
  if ((tid & 63) == 0) red[tid>>6] = s;
  __syncthreads();
  if (tid == 0) maskv[row] = ((red[0]+red[1]+red[2]+red[3]) == 0.f) ? 1.f : 0.f;
}

// ---------------- proj (MFMA, 3 GEMMs fused via blockIdx.z) ----------------
__global__ __launch_bounds__(256) void proj_mfma_kernel(const half_t* __restrict__ A0,
                                                        const half_t* __restrict__ A1,
                                                        const half_t* __restrict__ A2,
                                                        const half_t* __restrict__ W0,
                                                        const half_t* __restrict__ W1,
                                                        const half_t* __restrict__ W2,
                                                        const float* __restrict__ b0p,
                                                        const float* __restrict__ b1p,
                                                        const float* __restrict__ b2p,
                                                        half_t* __restrict__ H0,
                                                        half_t* __restrict__ H1,
                                                        half_t* __restrict__ H2)
{
  int z = blockIdx.z;
  int Mb = (z == 0) ? 100 : 64;
  if ((int)blockIdx.x >= Mb) return;
  const half_t* A  = (z==0) ? A0 : (z==1) ? A1 : A2;
  const half_t* Wt = (z==0) ? W0 : (z==1) ? W1 : W2;
  const float* bias = (z==0) ? b0p : (z==1) ? b1p : b2p;
  half_t* H = (z==0) ? H0 : (z==1) ? H1 : H2;
  int Kp = (z==0) ? VD : (z==1) ? QD : KGP;

  int w = threadIdx.x >> 6, lane = threadIdx.x & 63;
  int m0 = blockIdx.x*64 + w*16;
  int n0 = blockIdx.y*64;
  int lr = lane & 15, lc = lane >> 4;
  f32x4 acc[4];
#pragma unroll
  for (int nt=0;nt<4;nt++) acc[nt] = (f32x4)(0.f);
  const half_t* arow = A + (size_t)(m0 + lr)*Kp + lc*8;
  for (int k0 = 0; k0 < Kp; k0 += 32) {
    f16x8 a = *(const f16x8*)(arow + k0);
#pragma unroll
    for (int nt = 0; nt < 4; nt++) {
      f16x8 b = *(const f16x8*)(Wt + (size_t)(n0 + nt*16 + lr)*Kp + k0 + lc*8);
      acc[nt] = MFMA_F16(a, b, acc[nt]);
    }
  }
#pragma unroll
  for (int nt = 0; nt < 4; nt++) {
    float bb = bias[n0 + nt*16 + lr];
#pragma unroll
    for (int j = 0; j < 4; j++) {
      float vv = fmaxf(acc[nt][j] + bb, 0.f);
      H[(size_t)(m0 + lc*4 + j)*HH + n0 + nt*16 + lr] = (half_t)vv;
    }
  }
}

// ---------------- stageA v3 (LDS-transposed coalesced stores) ----------------
// grid (100, 8, RC), 256 thr = 4 waves; wave = 16 bv-rows x 256 c'.
// Phase 1: 16 swapped-operand MFMAs (A=T-frag -> D[m=c'][n=bv]); each lane's f16x4 goes to
// a wave-private LDS tile [16][256] with XOR-swizzled col4 ((t*4+lc)^(lr&14)): uniform
// 4 lanes/bank-pair = LDS floor. Phase 2 (no barrier, wave-private): 8x b128 reads
// (2 rows/instr, uniform banks) -> 8 global b128 stores = dense 512-B row segments.
// Kills R10's 1.57x HBM write amplification (32-B partial lines -> full lines).
__global__ __launch_bounds__(256) void stageA_mfma_kernel(const half_t* __restrict__ hv,
                                                          const half_t* __restrict__ Tpp,
                                                          half_t* __restrict__ u, int r0)
{
  __shared__ half_t tile[4][16][256];   // 32 KB, wave-private slices
  int rc = blockIdx.z; int r = r0 + rc;
  int w = threadIdx.x >> 6, lane = threadIdx.x & 63;
  int m0 = blockIdx.x*64 + w*16;
  int n0 = blockIdx.y*256;
  int lr = lane & 15, lc = lane >> 4;
  f16x8 bH = *(const f16x8*)(hv + (size_t)(m0 + lr)*HH + r*HDm + lc*8);
  const half_t* ta = Tpp + ((size_t)r << 16) + (size_t)n0*32 + lr*32 + lc*8;
  half_t* myt = &tile[w][0][0];
#pragma unroll
  for (int t = 0; t < 16; t++) {
    f16x8 aT = *(const f16x8*)(ta + t*512);
    f32x4 d = MFMA_F16(aT, bH, (f32x4)(0.f));
    f16x4 pk;
    pk[0] = (half_t)d[0]; pk[1] = (half_t)d[1];
    pk[2] = (half_t)d[2]; pk[3] = (half_t)d[3];
    int col4 = (t*4 + lc) ^ (lr & 14);              // swizzle keeps 8-B align
    *(f16x4*)(myt + lr*256 + col4*4) = pk;
  }
  // wave-private tile: per-wave DS ordering (lgkmcnt) suffices, no barrier
  half_t* ub = u + ((size_t)rc*NBV + m0)*2048 + n0;
  int hl = lane >> 5;          // which row of the pair
  int cc = lane & 31;          // 16-B chunk within row
#pragma unroll
  for (int i = 0; i < 8; i++) {
    int rrow = i*2 + hl;
    int pc4 = (cc*2) ^ (rrow & 14);                 // inverse swizzle (bit0 untouched)
    f16x8 val = *(const f16x8*)(myt + rrow*256 + pc4*4);
    *(f16x8*)(ub + (size_t)rrow*2048 + cc*8) = val;
  }
}

// ---------------- triBC (byte-exact R3 version: ~350 us measured) ----------------
#define WSTRIDE 2080   /* halves per g-plane in w frag buffer (pad vs 2048 to split banks) */
__global__ __launch_bounds__(256,2) void triBC_mfma_kernel(const half_t* __restrict__ hq,
                                                           const half_t* __restrict__ hk,
                                                           const half_t* __restrict__ u,
                                                           const float* __restrict__ maskv,
                                                           float* __restrict__ logits,
                                                           float* __restrict__ pm,
                                                           float* __restrict__ ps,
                                                           int r0, int RC, int isFirst, int isLast)
{
  __shared__ __align__(16) half_t smem[2048 + 2048 + 4*2*WSTRIDE];
  half_t* qtf = smem;
  half_t* ktf = smem + 2048;
  int tid = threadIdx.x;
  int w = tid >> 6, lane = tid & 63;
  half_t* wme = smem + 4096 + w*(2*WSTRIDE);
  int vt = blockIdx.x, b = blockIdx.y;
  int bv = b*VN + vt*4 + w;
  int lr = lane & 15, lc = lane >> 4;

  f32x4 acc[2][4][4];
#pragma unroll
  for (int g=0;g<2;g++)
#pragma unroll
    for (int mt=0;mt<4;mt++)
#pragma unroll
      for (int nt=0;nt<4;nt++) acc[g][mt][nt] = (f32x4)(0.f);

  // staging map: 256 threads stage 64 rows x 32 halves (4 thr/row, 8 halves each)
  int srow = tid >> 2, sch = tid & 3;
  const half_t* qsrc = hq + (size_t)(b*QN + srow)*HH + sch*8;
  const half_t* ksrc = hk + (size_t)(b*KN + srow)*HH + sch*8;
  int sdst = (srow>>4)*512 + ((srow&15) + sch*16)*8;

  for (int rc = 0; rc < RC; rc++) {
    int r = r0 + rc;
    __syncthreads();                                   // prev rank's C done
    // issue u' fragment loads early (coalesced 1KB per tile)
    const half_t* up = u + ((size_t)rc*NBV + bv)*2048;
    f16x8 ub[4];
#pragma unroll
    for (int nt=0;nt<4;nt++) ub[nt] = *(const f16x8*)(up + (nt*16+lr)*HDm + lc*8);
    // stage qt/kt frag-major
    *(f16x8*)&qtf[sdst] = *(const f16x8*)(qsrc + r*HDm);
    *(f16x8*)&ktf[sdst] = *(const f16x8*)(ksrc + r*HDm);
    __syncthreads();
    // stage B: w[q][zg] = sum_y qt[q][y] * u[y][zg]
    f16x8 qa[4];
#pragma unroll
    for (int mt=0;mt<4;mt++) qa[mt] = *(const f16x8*)&qtf[mt*512 + lane*8];
#pragma unroll
    for (int nt=0;nt<4;nt++) {
      f32x4 wv[4];
#pragma unroll
      for (int mt=0;mt<4;mt++) wv[mt] = MFMA_F16(qa[mt], ub[nt], (f32x4)(0.f));
      // scatter to frag-major fp16: g = lr&1, slot j = lr>>1
#pragma unroll
      for (int mt=0;mt<4;mt++) {
#pragma unroll
        for (int j=0;j<4;j++) {
          int dst = (lr&1)*WSTRIDE + mt*512 + (lc*4 + j + nt*16)*8 + (lr>>1);
          wme[dst] = (half_t)wv[mt][j];
        }
      }
    }
    __syncthreads();
    // stage C: logits[q][k][g] += sum_z w_g[q][z] * kt[k][z]
    f16x8 bk[4];
#pragma unroll
    for (int nt=0;nt<4;nt++) bk[nt] = *(const f16x8*)&ktf[nt*512 + lane*8];
#pragma unroll
    for (int g=0;g<2;g++) {
      f16x8 am[4];
#pragma unroll
      for (int mt=0;mt<4;mt++) am[mt] = *(const f16x8*)&wme[g*WSTRIDE + mt*512 + lane*8];
#pragma unroll
      for (int mt=0;mt<4;mt++)
#pragma unroll
        for (int nt=0;nt<4;nt++)
          acc[g][mt][nt] = MFMA_F16(am[mt], bk[nt], acc[g][mt][nt]);
    }
  }

  // epilogue
  float mk = maskv[bv];
  float* lbase = logits + (size_t)bv*QN*KN*GG;
#pragma unroll
  for (int mt=0;mt<4;mt++)
#pragma unroll
    for (int nt=0;nt<4;nt++)
#pragma unroll
      for (int j=0;j<4;j++) {
        size_t off = ((size_t)(mt*16 + lc*4 + j)*KN + nt*16 + lr)*GG;
        float g0 = acc[0][mt][nt][j], g1 = acc[1][mt][nt][j];
        if (!isFirst) { float2 prev = *(const float2*)(lbase + off); g0 += prev.x; g1 += prev.y; }
        if (isLast && mk != 0.f) { g0 = MASK_VAL; g1 = MASK_VAL; }
        *(float2*)(lbase + off) = make_float2(g0, g1);
        acc[0][mt][nt][j] = g0; acc[1][mt][nt][j] = g1;
      }
  if (isLast) {
#pragma unroll
    for (int g=0; g<2; g++) {
      float mloc = acc[g][0][0][0];
#pragma unroll
      for (int mt=0;mt<4;mt++)
#pragma unroll
        for (int nt=0;nt<4;nt++)
#pragma unroll
          for (int j=0;j<4;j++) mloc = fmaxf(mloc, acc[g][mt][nt][j]);
      float sloc = 0.f;
#pragma unroll
      for (int mt=0;mt<4;mt++)
#pragma unroll
        for (int nt=0;nt<4;nt++)
#pragma unroll
          for (int j=0;j<4;j++) sloc += __expf(acc[g][mt][nt][j] - mloc);
#pragma unroll
      for (int off2=1; off2<64; off2<<=1) {
        float m2 = __shfl_xor(mloc, off2);
        float s2 = __shfl_xor(sloc, off2);
        float mn = fmaxf(mloc, m2);
        sloc = sloc*__expf(mloc-mn) + s2*__expf(m2-mn);
        mloc = mn;
      }
      if (lane == 0) { pm[(size_t)bv*GG + g] = mloc; ps[(size_t)bv*GG + g] = sloc; }
    }
  }
}

// ---------------- combine per-(b,g) partials over 100 v ----------------
__global__ __launch_bounds__(64) void combine_kernel(const float* __restrict__ pm,
                                                     const float* __restrict__ ps,
                                                     float* __restrict__ Mg, float* __restrict__ Sg)
{
  int bg = blockIdx.x; int b = bg >> 1, g = bg & 1;
  int lane = threadIdx.x;
  float m = pm[((size_t)b*VN + lane)*GG + g];
  float s = ps[((size_t)b*VN + lane)*GG + g];
  if (lane + 64 < VN) {
    float m2 = pm[((size_t)b*VN + lane + 64)*GG + g];
    float s2 = ps[((size_t)b*VN + lane + 64)*GG + g];
    float mn = fmaxf(m, m2);
    s = s*__expf(m-mn) + s2*__expf(m2-mn); m = mn;
  }
#pragma unroll
  for (int off=1; off<64; off<<=1) {
    float m2 = __shfl_xor(m, off);
    float s2 = __shfl_xor(s, off);
    float mn = fmaxf(m, m2);
    s = s*__expf(m-mn) + s2*__expf(m2-mn);
    m = mn;
  }
  if (lane == 0) { Mg[b*GG+g] = m; Sg[b*GG+g] = s; }
}

// ---------------- p = exp(logits - M)/S ----------------
__global__ __launch_bounds__(256) void pwrite_kernel(const float* __restrict__ logits,
                                                     const float* __restrict__ Mg,
                                                     const float* __restrict__ Sg,
                                                     float* __restrict__ p)
{
  size_t stride = (size_t)gridDim.x * 256;
  const size_t n4 = LOGN/4;
  for (size_t idx = (size_t)blockIdx.x*256 + threadIdx.x; idx < n4; idx += stride){
    size_t e = idx*4;
    int b = (int)(e / ((size_t)VN*QN*KN*GG));
    float M0 = Mg[b*2], M1 = Mg[b*2+1];
    float iS0 = 1.f/Sg[b*2], iS1 = 1.f/Sg[b*2+1];
    float4 x = *(const float4*)&logits[e];
    float4 o;
    o.x = __expf(x.x - M0)*iS0;
    o.y = __expf(x.y - M1)*iS1;
    o.z = __expf(x.z - M0)*iS0;
    o.w = __expf(x.w - M1)*iS1;
    *(float4*)&p[e] = o;
  }
}

extern "C" void kernel_launch(void* const* d_in, const int* in_sizes, int n_in,
                              void* d_out, int out_size, void* d_ws, size_t ws_size,
                              hipStream_t stream)
{
  const float* v   = (const float*)d_in[0];
  const float* q   = (const float*)d_in[1];
  const float* kg  = (const float*)d_in[2];
  const float* Wv  = (const float*)d_in[3];
  const float* bv  = (const float*)d_in[4];
  const float* Wq  = (const float*)d_in[5];
  const float* bq  = (const float*)d_in[6];
  const float* Wkg = (const float*)d_in[7];
  const float* bkg = (const float*)d_in[8];
  const float* Tg  = (const float*)d_in[9];
  float* p_out  = (float*)d_out;
  float* logits = p_out + LOGN;

  char* ws = (char*)d_ws;
  size_t off = 0;
  auto alloc = [&](size_t bytes) -> char* {
    char* ptr = ws + off;
    off = (off + bytes + 255) & ~(size_t)255;
    return ptr;
  };
  half_t* h_v16 = (half_t*)alloc((size_t)NBV*HH*2);
  half_t* h_q16 = (half_t*)alloc((size_t)Bb*QN*HH*2);
  half_t* h_k16 = (half_t*)alloc((size_t)Bb*KN*HH*2);
  half_t* v16   = (half_t*)alloc((size_t)NBV*VD*2);
  half_t* q16   = (half_t*)alloc((size_t)Bb*QN*QD*2);
  half_t* k16   = (half_t*)alloc((size_t)Bb*KN*KGP*2);
  half_t* Wvt   = (half_t*)alloc((size_t)HH*VD*2);
  half_t* Wqt   = (half_t*)alloc((size_t)HH*QD*2);
  half_t* Wkt   = (half_t*)alloc((size_t)HH*KGP*2);
  half_t* Tpp   = (half_t*)alloc((size_t)32*65536*2);
  float* maskv  = (float*)alloc((size_t)NBV*4);
  float* pm     = (float*)alloc((size_t)NBV*GG*4);
  float* ps     = (float*)alloc((size_t)NBV*GG*4);
  float* Mg     = (float*)alloc(128*4);
  float* Sg     = (float*)alloc(128*4);
  size_t WS_FIXED = off;
  const size_t USZB = (size_t)NBV*2048*2;   // 26,214,400 bytes per r-slice

  int RC; half_t* u;
  if      (WS_FIXED + 32*USZB <= ws_size) { RC = 32; u = (half_t*)(ws + off); }
  else if (WS_FIXED + 16*USZB <= ws_size) { RC = 16; u = (half_t*)(ws + off); }
  else if (WS_FIXED +  8*USZB <= ws_size) { RC =  8; u = (half_t*)(ws + off); }
  else { RC = 8; u = (half_t*)p_out; }      // p region = exactly 8 slices; rewritten at end

  // fused preproc + mask
  preproc_kernel<<<(unsigned)((PTOT + 255)/256),256,0,stream>>>(v, q, kg, Wv, Wq, Wkg, Tg,
                                                                v16, q16, k16, Wvt, Wqt, Wkt, Tpp);
  mask_kernel<<<NBV,256,0,stream>>>(v, maskv);

  // fused projections (z = 0:v, 1:q, 2:kg)
  proj_mfma_kernel<<<dim3(100,16,3),256,0,stream>>>(v16, q16, k16, Wvt, Wqt, Wkt,
                                                    bv, bq, bkg, h_v16, h_q16, h_k16);

  for (int r0 = 0; r0 < RR; r0 += RC) {
    stageA_mfma_kernel<<<dim3(100,8,RC),256,0,stream>>>(h_v16, Tpp, u, r0);
    triBC_mfma_kernel<<<dim3(25,Bb),256,0,stream>>>(h_q16, h_k16, u, maskv, logits, pm, ps,
                                                    r0, RC, (r0==0)?1:0, (r0+RC>=RR)?1:0);
  }
  combine_kernel<<<128,64,0,stream>>>(pm, ps, Mg, Sg);
  pwrite_kernel<<<2048,256,0,stream>>>(logits, Mg, Sg, p_out);
}